// Round 20
// baseline (844.498 us; speedup 1.0000x reference)
//
#include <hip/hip_runtime.h>
#include <hip/hip_bf16.h>
#include <math.h>

// ---------------- problem constants ----------------
#define B_ROWS 4096
#define DZ     2048
#define DE     128
#define M_EXP  32
#define H_DIM  1024
#define NBIG   32768          // M_EXP * H_DIM
#define NEXTRA 256            // 128 gate + 3 base + 125 zero-pad
#define NTOT   (NBIG + NEXTRA)   // 33024 = 129 * 256
#define W1_LD  (DZ + DE)      // 2176

typedef _Float16 half8 __attribute__((ext_vector_type(8)));
typedef float    f32x4 __attribute__((ext_vector_type(4)));

#define AS1 __attribute__((address_space(1)))
#define AS3 __attribute__((address_space(3)))

__device__ __forceinline__ void async_copy16(const void* g, void* l) {
  __builtin_amdgcn_global_load_lds((const AS1 void*)g, (AS3 void*)l, 16, 0, 0);
}

__device__ __forceinline__ half8 cvt8(const float4& a, const float4& b) {
  half8 h = {(_Float16)a.x, (_Float16)a.y, (_Float16)a.z, (_Float16)a.w,
             (_Float16)b.x, (_Float16)b.y, (_Float16)b.z, (_Float16)b.w};
  return h;
}

// exact-GELU via A&S 7.1.26 erf (|eps| <= 1.5e-7)
__device__ __forceinline__ float gelu_f(float x) {
  float u = fabsf(x) * 0.70710678118654752f;
  float t = 1.0f / fmaf(0.3275911f, u, 1.0f);
  float poly = t * fmaf(t, fmaf(t, fmaf(t, fmaf(t, 1.061405429f, -1.453152027f),
                                        1.421413741f), -0.284496736f), 0.254829592f);
  float er = 1.0f - poly * __expf(-u * u);
  er = copysignf(er, x);
  return 0.5f * x * (1.0f + er);
}

// ---------------- z -> f16, packed in MFMA A-fragment order ----------------
// frag unit = 16 rows x 32 K. zpk[((r16*64 + kt)*512) + (rl + 16*lg)*8 + e]
//   = (f16) z[r16*16 + rl][kt*32 + lg*8 + e]
__global__ __launch_bounds__(256) void k_cvt_z(const float* __restrict__ z,
                                               _Float16* __restrict__ zpk) {
  long g = (long)blockIdx.x * 256 + threadIdx.x;   // 1M threads, 8 elems each
  int row = (int)(g >> 8);
  int k0  = ((int)g & 255) * 8;
  float4 a = *(const float4*)(z + (long)row * DZ + k0);
  float4 b = *(const float4*)(z + (long)row * DZ + k0 + 4);
  int r16 = row >> 4, rl = row & 15, kt = k0 >> 5, lg = (k0 >> 3) & 3;
  long dst = ((long)(r16 * 64 + kt) << 9) + (rl + 16 * lg) * 8;
  *(half8*)(zpk + dst) = cvt8(a, b);
}

// ---------------- W1 z-part -> f16 packed rows; tail -> hbias = E.W1e + b1 ----------------
__global__ __launch_bounds__(256) void k_cvt_w1(const float* __restrict__ W1,
                                                const float* __restrict__ E,
                                                const float* __restrict__ b1,
                                                _Float16* __restrict__ W1h,
                                                float* __restrict__ hbias) {
  const long n = blockIdx.x;        // 0..32767
  const int  t = threadIdx.x;       // 256
  const float* src = W1 + n * W1_LD;
  float4 a = *(const float4*)(src + t * 8);
  float4 b = *(const float4*)(src + t * 8 + 4);
  *(half8*)(W1h + n * DZ + t * 8) = cvt8(a, b);
  if (t < 32) {
    int m = (int)(n >> 10);
    float4 w = *(const float4*)(src + DZ + t * 4);
    float4 e = *(const float4*)(E + m * DE + t * 4);
    float p = w.x * e.x + w.y * e.y + w.z * e.z + w.w * e.w;
    p += __shfl_xor(p, 16);
    p += __shfl_xor(p, 8);
    p += __shfl_xor(p, 4);
    p += __shfl_xor(p, 2);
    p += __shfl_xor(p, 1);
    if (t == 0) hbias[n] = p + b1[n];
  }
}

// ---------------- gate_W / base_W -> f16 rows appended; pad rows zeroed ----------------
__global__ __launch_bounds__(256) void k_cvt_small(const float* __restrict__ gate_W,
                                                   const float* __restrict__ base_W,
                                                   _Float16* __restrict__ W1h) {
  int r = blockIdx.x;               // 0..255
  int t = threadIdx.x;
  const float* src = nullptr;
  if (r < 128)       src = gate_W + (long)r * DZ;
  else if (r < 131)  src = base_W + (long)(r - 128) * DZ;
  _Float16* dst = W1h + (long)(NBIG + r) * DZ + t * 8;
  if (src) {
    float4 a = *(const float4*)(src + t * 8);
    float4 b = *(const float4*)(src + t * 8 + 4);
    *(half8*)dst = cvt8(a, b);
  } else {
    half8 zv = {(_Float16)0, (_Float16)0, (_Float16)0, (_Float16)0,
                (_Float16)0, (_Float16)0, (_Float16)0, (_Float16)0};
    *(half8*)dst = zv;
  }
}

// ======== 128x256 GEMM: R15 + 2 K-tiles/barrier (ring-4), ORDER-PINNED staging ========
// R18's NaN mechanism: if any A-load issues before the stage copies, the auto-wait
// before MFMA32(AFo) retires A-loads but NOT the (younger) stage copies -> stale LDS
// across the barrier. Invariant restored by pinning "stage first" with sched_barrier(0):
// then ANY wait retiring the A-loads necessarily retires the older stage copies, so the
// compiler's own register-dependency wait before MFMA32(AFo) certifies the stage each
// phase, before the next BAR. 32 barriers instead of 64.
// 4 waves 2Mx2N; wave owns 64x128 = 4x8 mfma_16x16x32_f16 frags (acc 128).
// Phase p (tiles kt=2p, 2p+1; read slot pair s0,s0|1; stage pair s0^2 = tiles kt+2,kt+3):
//   BAR; 8 ds_reads(s0); STAGE pair (8 gload_lds); SBAR0; load AFo(kt+1);
//   MFMA32(AFe=kt); load AFe(kt+2); 8 ds_reads(s0|1); MFMA32(AFo).
// Slot safety: write pair = read pair ^ 2 (disjoint); pair read in p staged in p-1,
// certified by p-1's auto-wait + BAR(p). Swizzle: g ^ ((r>>1)&3) (0-conflict, HW-ver).
__global__ __launch_bounds__(256, 2) void k_gemm(const _Float16* __restrict__ Apk,  // zpk
                                                 const _Float16* __restrict__ Bm,   // W1h
                                                 const float* __restrict__ hbias,   // [NBIG]
                                                 const float* __restrict__ W2,      // [M,3,H]
                                                 float* __restrict__ Lout,          // [B,96] atomic
                                                 float* __restrict__ qraw) {        // [B,256]
  __shared__ _Float16 sm[4][8192];   // [slot][B tile 256 rows x 32 K], 64 KiB

  // XCD-aware bijective swizzle: 4128 blocks = 8 * 516; tM fastest (B-panel L2 reuse x32)
  int flat = blockIdx.y * gridDim.x + blockIdx.x;
  int wg   = (flat & 7) * 516 + (flat >> 3);
  const int tN = wg >> 5;           // 0..128 (256-col tile)
  const int tM = wg & 31;           // 0..31  (128-row tile)

  const int tid = threadIdx.x;
  const int w = tid >> 6, l = tid & 63;
  const int wm = w >> 1, wn = w & 1;       // wave grid 2x2
  const int rl = l & 15, lg = l >> 4;

  // ---- B staging (linear LDS dest, inverse-swizzled global src); 4 copies/tile ----
  const int srow  = tid >> 2;                              // 0..63
  const int sgoff = ((tid & 3) ^ ((srow >> 1) & 3)) * 8;   // swizzled k-granule (elems)
  const _Float16* gB = Bm + (long)(tN * 256 + srow) * DZ + sgoff;

#define STAGE_B(sb, kt) do { \
    async_copy16(gB + (kt) * 32,            &sm[sb][tid * 8]); \
    async_copy16(gB + 64 * DZ + (kt) * 32,  &sm[sb][2048 + tid * 8]); \
    async_copy16(gB + 128 * DZ + (kt) * 32, &sm[sb][4096 + tid * 8]); \
    async_copy16(gB + 192 * DZ + (kt) * 32, &sm[sb][6144 + tid * 8]); } while (0)

  // ---- A packed frag loads: frag (r16, kt) at Apk[(r16*64+kt)*512 + l*8], coalesced ----
  // wave rows: tM*128 + wm*64 + i*16 -> r16 = tM*8 + wm*4 + i
  const _Float16* gA = Apk + ((long)(tM * 8 + wm * 4) << 9) * 64 + l * 8;

#define RD_AG(dst, kt) do { _Pragma("unroll") for (int _i = 0; _i < 4; ++_i) \
    dst[_i] = *(const half8*)(gA + ((long)(_i * 64 + (kt)) << 9)); } while (0)

  // ---- B fragment read offsets (elems); verified 0-conflict pattern ----
  const int aswz  = (lg ^ ((rl >> 1) & 3)) * 8;
  const int offB0 = (wn * 128 + rl) * 32 + aswz;           // + j*512, j=0..7

  half8 AFe[4], AFo[4], bf[8];
  f32x4 acc[4][8];
  f32x4 z4 = {0.f, 0.f, 0.f, 0.f};
#pragma unroll
  for (int i = 0; i < 4; ++i)
#pragma unroll
    for (int j = 0; j < 8; ++j) acc[i][j] = z4;

#define RD_B8(sl) do { _Pragma("unroll") for (int _j = 0; _j < 8; ++_j) \
    bf[_j] = *(const half8*)&sm[sl][offB0 + _j * 512]; } while (0)

#define MFMA32(af_) do { \
    _Pragma("unroll") for (int _i = 0; _i < 4; ++_i) \
    _Pragma("unroll") for (int _j = 0; _j < 8; ++_j) \
      acc[_i][_j] = __builtin_amdgcn_mfma_f32_16x16x32_f16(af_[_i], bf[_j], acc[_i][_j], 0, 0, 0); \
  } while (0)

#define BAR() do { asm volatile("" ::: "memory"); __builtin_amdgcn_s_barrier(); asm volatile("" ::: "memory"); } while (0)
#define SBAR0 __builtin_amdgcn_sched_barrier(0)
#define VM0 asm volatile("s_waitcnt vmcnt(0)" ::: "memory")

  // phase: tiles kt,kt+1 from slots s0,s0|1; stage tiles kt+2,kt+3 into s0^2 pair.
  // "Stage first" pinned by SBAR0 -> any A-load wait certifies the stage.
#define PHASE(s0, kt) do { \
    BAR(); \
    RD_B8(s0); \
    STAGE_B((s0) ^ 2, (kt) + 2); \
    STAGE_B(((s0) ^ 2) | 1, (kt) + 3); \
    SBAR0; \
    RD_AG(AFo, (kt) + 1); \
    MFMA32(AFe); \
    RD_AG(AFe, (kt) + 2); \
    RD_B8((s0) | 1); \
    MFMA32(AFo); } while (0)
  // phase 30 variant: stages last pair, no AFe-next load needed beyond 63
#define PHASE_S(s0, kt) do { \
    BAR(); \
    RD_B8(s0); \
    STAGE_B((s0) ^ 2, (kt) + 2); \
    STAGE_B(((s0) ^ 2) | 1, (kt) + 3); \
    SBAR0; \
    RD_AG(AFo, (kt) + 1); \
    MFMA32(AFe); \
    RD_AG(AFe, (kt) + 2); \
    RD_B8((s0) | 1); \
    MFMA32(AFo); } while (0)
  // final phase: tiles kt,kt+1, no staging, no next-A
#define PHASE_LAST(s0, kt) do { \
    BAR(); \
    RD_B8(s0); \
    RD_AG(AFo, (kt) + 1); \
    MFMA32(AFe); \
    RD_B8((s0) | 1); \
    MFMA32(AFo); } while (0)

  // ---- prologue: stage tiles 0,1 (slots 0,1); load A(0)->AFe; full drain (once) ----
  STAGE_B(0, 0);
  STAGE_B(1, 1);
  RD_AG(AFe, 0);
  VM0;

  // ---- main loop: phases 0..29 (tiles 0..59; stage 2..61) ----
#pragma unroll 1
  for (int n = 0; n < 15; ++n) {
    PHASE(0, 4 * n);
    PHASE(2, 4 * n + 2);
  }
  // phase 30: tiles 60,61; stage 62,63 (slots 2,3)
  PHASE_S(0, 60);
  // phase 31: tiles 62,63 (certified by phase 30's A-wait + BAR)
  PHASE_LAST(2, 62);

  // ---- epilogue ----
  // C/D 16x16 layout: col = rl, row = lg*4 + reg
  if (tN < 128) {
    const int m = tN >> 2;                    // expert (4 N-tiles of 256 per expert)
    float hb[8], w2v[3][8];
#pragma unroll
    for (int j = 0; j < 8; ++j) {
      int gcol = tN * 256 + wn * 128 + j * 16 + rl;     // global big col
      int he   = gcol & (H_DIM - 1);                    // col within expert
      hb[j] = hbias[gcol];
#pragma unroll
      for (int o = 0; o < 3; ++o) w2v[o][j] = W2[((long)m * 3 + o) * H_DIM + he];
    }
#pragma unroll
    for (int i = 0; i < 4; ++i) {
      const int growb = tM * 128 + wm * 64 + i * 16 + lg * 4;
#pragma unroll
      for (int r = 0; r < 4; ++r) {
        int grow = growb + r;
        float hv[8];
#pragma unroll
        for (int j = 0; j < 8; ++j) hv[j] = gelu_f(acc[i][j][r] + hb[j]);
#pragma unroll
        for (int o = 0; o < 3; ++o) {
          float p = 0.f;
#pragma unroll
          for (int j = 0; j < 8; ++j) p = fmaf(hv[j], w2v[o][j], p);
          p += __shfl_xor(p, 1);
          p += __shfl_xor(p, 2);
          p += __shfl_xor(p, 4);
          p += __shfl_xor(p, 8);
          if (rl == o) atomicAdd(&Lout[(long)grow * 96 + m * 3 + o], p);
        }
      }
    }
  } else {
    // raw gate/base pre-activations (global cols 32768..33023)
#pragma unroll
    for (int i = 0; i < 4; ++i) {
      const int growb = tM * 128 + wm * 64 + i * 16 + lg * 4;
#pragma unroll
      for (int r = 0; r < 4; ++r) {
        int grow = growb + r;
        int c0 = wn * 128 + rl;
#pragma unroll
        for (int j = 0; j < 8; ++j)
          qraw[(long)grow * 256 + c0 + j * 16] = acc[i][j][r];
      }
    }
  }
}

// ---------------- post: q normalize, sims, L += base + b2 ----------------
__global__ __launch_bounds__(128) void k_post(const float* __restrict__ qraw,
                                              const float* __restrict__ gate_b,
                                              const float* __restrict__ base_b,
                                              const float* __restrict__ E,
                                              const float* __restrict__ b2,
                                              float* __restrict__ out) {
  const int b = blockIdx.x;
  const int t = threadIdx.x;          // 128
  __shared__ float qs[DE];
  __shared__ float invE[M_EXP];
  __shared__ float wsum[2];
  __shared__ float pA[M_EXP], pB[M_EXP];

  if (t < 32) {
    float ss = 0.f;
    const float* er = E + t * DE;
    for (int e = 0; e < DE; ++e) { float v = er[e]; ss += v * v; }
    invE[t] = 1.0f / fmaxf(sqrtf(ss), 1e-12f);
  }

  float val = qraw[(long)b * 256 + t] + gate_b[t];
  float ss = val * val;
  ss += __shfl_xor(ss, 1);  ss += __shfl_xor(ss, 2);  ss += __shfl_xor(ss, 4);
  ss += __shfl_xor(ss, 8);  ss += __shfl_xor(ss, 16); ss += __shfl_xor(ss, 32);
  if ((t & 63) == 0) wsum[t >> 6] = ss;
  __syncthreads();
  float inv = 1.0f / fmaxf(sqrtf(wsum[0] + wsum[1]), 1e-12f);
  qs[t] = val * inv;
  __syncthreads();

  {
    int m = t & 31, hf = t >> 5;
    const float* er = E + m * DE + hf * 32;
    const float* qq = qs + hf * 32;
    float p = 0.f;
#pragma unroll
    for (int e = 0; e < 32; ++e) p += qq[e] * er[e];
    p += __shfl_xor(p, 32);
    if (t < 32) pA[m] = p;
    else if (t >= 64 && t < 96) pB[m] = p;
    __syncthreads();
    if (t < 32) out[(long)B_ROWS * 96 + (long)b * 32 + t] = (pA[t] + pB[t]) * invE[t];
  }

  if (t < 96) {
    int o = t % 3;
    float bv = qraw[(long)b * 256 + 128 + o] + base_b[o];
    out[(long)b * 96 + t] += bv + b2[t];
  }
}

// ---------------- launch ----------------
extern "C" void kernel_launch(void* const* d_in, const int* in_sizes, int n_in,
                              void* d_out, int out_size, void* d_ws, size_t ws_size,
                              hipStream_t stream) {
  const float* z      = (const float*)d_in[0];
  const float* base_W = (const float*)d_in[1];
  const float* base_b = (const float*)d_in[2];
  const float* gate_W = (const float*)d_in[3];
  const float* gate_b = (const float*)d_in[4];
  const float* E      = (const float*)d_in[5];
  const float* W1     = (const float*)d_in[6];
  const float* b1     = (const float*)d_in[7];
  const float* W2     = (const float*)d_in[8];
  const float* b2     = (const float*)d_in[9];
  float* out = (float*)d_out;

  char* ws = (char*)d_ws;
  const size_t off_zh    = 0;                                   // B*DZ*2 (packed)
  const size_t off_w1h   = off_zh  + (size_t)B_ROWS * DZ * 2;   // NTOT*DZ*2
  const size_t off_hbias = off_w1h + (size_t)NTOT * DZ * 2;     // NBIG*4
  const size_t off_qraw  = off_hbias + (size_t)NBIG * 4;        // B*256*4
  _Float16* zpk   = (_Float16*)(ws + off_zh);
  _Float16* W1h   = (_Float16*)(ws + off_w1h);
  float*    hbias = (float*)(ws + off_hbias);
  float*    qraw  = (float*)(ws + off_qraw);

  // L must start at 0 every call (epilogue atomically accumulates into it)
  hipMemsetAsync(d_out, 0, (size_t)B_ROWS * 96 * sizeof(float), stream);

  k_cvt_z<<<(B_ROWS * DZ) / (256 * 8), 256, 0, stream>>>(z, zpk);
  k_cvt_w1<<<NBIG, 256, 0, stream>>>(W1, E, b1, W1h, hbias);
  k_cvt_small<<<NEXTRA, 256, 0, stream>>>(gate_W, base_W, W1h);
  k_gemm<<<dim3(129, 32), 256, 0, stream>>>(zpk, W1h, hbias, W2, out, qraw);
  k_post<<<B_ROWS, 128, 0, stream>>>(qraw, gate_b, base_b, E, b2, out);
}

// Round 21
// 760.938 us; speedup vs baseline: 1.1098x; 1.1098x over previous
//
#include <hip/hip_runtime.h>
#include <hip/hip_bf16.h>
#include <math.h>

// ---------------- problem constants ----------------
#define B_ROWS 4096
#define DZ     2048
#define DE     128
#define M_EXP  32
#define H_DIM  1024
#define NBIG   32768          // M_EXP * H_DIM
#define NEXTRA 256            // 128 gate + 3 base + 125 zero-pad
#define NTOT   (NBIG + NEXTRA)   // 33024 = 129 * 256
#define W1_LD  (DZ + DE)      // 2176

typedef _Float16 half8 __attribute__((ext_vector_type(8)));
typedef float    f32x4 __attribute__((ext_vector_type(4)));

#define AS1 __attribute__((address_space(1)))
#define AS3 __attribute__((address_space(3)))

__device__ __forceinline__ void async_copy16(const void* g, void* l) {
  __builtin_amdgcn_global_load_lds((const AS1 void*)g, (AS3 void*)l, 16, 0, 0);
}

__device__ __forceinline__ half8 cvt8(const float4& a, const float4& b) {
  half8 h = {(_Float16)a.x, (_Float16)a.y, (_Float16)a.z, (_Float16)a.w,
             (_Float16)b.x, (_Float16)b.y, (_Float16)b.z, (_Float16)b.w};
  return h;
}

// exact-GELU via A&S 7.1.26 erf (|eps| <= 1.5e-7)
__device__ __forceinline__ float gelu_f(float x) {
  float u = fabsf(x) * 0.70710678118654752f;
  float t = 1.0f / fmaf(0.3275911f, u, 1.0f);
  float poly = t * fmaf(t, fmaf(t, fmaf(t, fmaf(t, 1.061405429f, -1.453152027f),
                                        1.421413741f), -0.284496736f), 0.254829592f);
  float er = 1.0f - poly * __expf(-u * u);
  er = copysignf(er, x);
  return 0.5f * x * (1.0f + er);
}

// ---------------- z -> f16, packed in MFMA A-fragment order ----------------
// frag unit = 16 rows x 32 K. zpk[((r16*64 + kt)*512) + (rl + 16*lg)*8 + e]
//   = (f16) z[r16*16 + rl][kt*32 + lg*8 + e]
__global__ __launch_bounds__(256) void k_cvt_z(const float* __restrict__ z,
                                               _Float16* __restrict__ zpk) {
  long g = (long)blockIdx.x * 256 + threadIdx.x;   // 1M threads, 8 elems each
  int row = (int)(g >> 8);
  int k0  = ((int)g & 255) * 8;
  float4 a = *(const float4*)(z + (long)row * DZ + k0);
  float4 b = *(const float4*)(z + (long)row * DZ + k0 + 4);
  int r16 = row >> 4, rl = row & 15, kt = k0 >> 5, lg = (k0 >> 3) & 3;
  long dst = ((long)(r16 * 64 + kt) << 9) + (rl + 16 * lg) * 8;
  *(half8*)(zpk + dst) = cvt8(a, b);
}

// ---------------- W1 z-part -> f16 packed rows; tail -> hbias = E.W1e + b1 ----------------
__global__ __launch_bounds__(256) void k_cvt_w1(const float* __restrict__ W1,
                                                const float* __restrict__ E,
                                                const float* __restrict__ b1,
                                                _Float16* __restrict__ W1h,
                                                float* __restrict__ hbias) {
  const long n = blockIdx.x;        // 0..32767
  const int  t = threadIdx.x;       // 256
  const float* src = W1 + n * W1_LD;
  float4 a = *(const float4*)(src + t * 8);
  float4 b = *(const float4*)(src + t * 8 + 4);
  *(half8*)(W1h + n * DZ + t * 8) = cvt8(a, b);
  if (t < 32) {
    int m = (int)(n >> 10);
    float4 w = *(const float4*)(src + DZ + t * 4);
    float4 e = *(const float4*)(E + m * DE + t * 4);
    float p = w.x * e.x + w.y * e.y + w.z * e.z + w.w * e.w;
    p += __shfl_xor(p, 16);
    p += __shfl_xor(p, 8);
    p += __shfl_xor(p, 4);
    p += __shfl_xor(p, 2);
    p += __shfl_xor(p, 1);
    if (t == 0) hbias[n] = p + b1[n];
  }
}

// ---------------- gate_W / base_W -> f16 rows appended; pad rows zeroed ----------------
__global__ __launch_bounds__(256) void k_cvt_small(const float* __restrict__ gate_W,
                                                   const float* __restrict__ base_W,
                                                   _Float16* __restrict__ W1h) {
  int r = blockIdx.x;               // 0..255
  int t = threadIdx.x;
  const float* src = nullptr;
  if (r < 128)       src = gate_W + (long)r * DZ;
  else if (r < 131)  src = base_W + (long)(r - 128) * DZ;
  _Float16* dst = W1h + (long)(NBIG + r) * DZ + t * 8;
  if (src) {
    float4 a = *(const float4*)(src + t * 8);
    float4 b = *(const float4*)(src + t * 8 + 4);
    *(half8*)dst = cvt8(a, b);
  } else {
    half8 zv = {(_Float16)0, (_Float16)0, (_Float16)0, (_Float16)0,
                (_Float16)0, (_Float16)0, (_Float16)0, (_Float16)0};
    *(half8*)dst = zv;
  }
}

// ======== 128x256 GEMM: A packed global->reg (coalesced), B-only ring-3 LDS ========
// Best verified configuration (R15/R19): ds_read_b128 runs at 85 B/cy (m134) -> removing A
// from LDS cuts reads 1/3; B-only LDS ~1020 cy/step ~ MFMA 1024 cy.
// 4 waves 2Mx2N; wave owns 64x128 = 4x8 mfma_16x16x32_f16 frags (acc 128).
// Per tile t (slot s=t%3), ONE barrier:
//   BAR; 8 ds_reads B(t); 4-copy stage B(t+2); 4 coalesced A-frag loads (t+1, ping-pong);
//   VM8 (count-robust cert: retires ALL of tile t-1's 8 issues regardless of intra-tile
//   compiler ordering); 32 MFMA.
// B(t) read-safety: staged at t-2, certified by VM8@t-1 + BAR(t). Slot overwrite: reads of
// slot (t+2)%3=(t-1)%3 finished before BAR(t). Swizzle: g ^ ((r>>1)&3) (0-conflict, HW-ver).
__global__ __launch_bounds__(256, 2) void k_gemm(const _Float16* __restrict__ Apk,  // zpk
                                                 const _Float16* __restrict__ Bm,   // W1h
                                                 const float* __restrict__ hbias,   // [NBIG]
                                                 const float* __restrict__ W2,      // [M,3,H]
                                                 float* __restrict__ Lout,          // [B,96] atomic
                                                 float* __restrict__ qraw) {        // [B,256]
  __shared__ _Float16 sm[3][8192];   // [slot][B tile 256 rows x 32 K], 48 KiB

  // XCD-aware bijective swizzle: 4128 blocks = 8 * 516; tM fastest (B-panel L2 reuse x32)
  int flat = blockIdx.y * gridDim.x + blockIdx.x;
  int wg   = (flat & 7) * 516 + (flat >> 3);
  const int tN = wg >> 5;           // 0..128 (256-col tile)
  const int tM = wg & 31;           // 0..31  (128-row tile)

  const int tid = threadIdx.x;
  const int w = tid >> 6, l = tid & 63;
  const int wm = w >> 1, wn = w & 1;       // wave grid 2x2
  const int rl = l & 15, lg = l >> 4;

  // ---- B staging (linear LDS dest, inverse-swizzled global src); 4 copies/thread ----
  const int srow  = tid >> 2;                              // 0..63
  const int sgoff = ((tid & 3) ^ ((srow >> 1) & 3)) * 8;   // swizzled k-granule (elems)
  const _Float16* gB = Bm + (long)(tN * 256 + srow) * DZ + sgoff;

#define STAGE_B(sb, kt) do { \
    async_copy16(gB + (kt) * 32,            &sm[sb][tid * 8]); \
    async_copy16(gB + 64 * DZ + (kt) * 32,  &sm[sb][2048 + tid * 8]); \
    async_copy16(gB + 128 * DZ + (kt) * 32, &sm[sb][4096 + tid * 8]); \
    async_copy16(gB + 192 * DZ + (kt) * 32, &sm[sb][6144 + tid * 8]); } while (0)

  // ---- A packed frag loads: frag (r16, kt) at Apk[(r16*64+kt)*512 + l*8], coalesced ----
  // wave rows: tM*128 + wm*64 + i*16 -> r16 = tM*8 + wm*4 + i
  const _Float16* gA = Apk + ((long)(tM * 8 + wm * 4) << 9) * 64 + l * 8;

#define RD_AG(dst, kt) do { _Pragma("unroll") for (int _i = 0; _i < 4; ++_i) \
    dst[_i] = *(const half8*)(gA + ((long)(_i * 64 + (kt)) << 9)); } while (0)

  // ---- B fragment read offsets (elems); verified 0-conflict pattern ----
  const int aswz  = (lg ^ ((rl >> 1) & 3)) * 8;
  const int offB0 = (wn * 128 + rl) * 32 + aswz;           // + j*512, j=0..7

  half8 AFe[4], AFo[4], bf03[4], bf47[4];
  f32x4 acc[4][8];
  f32x4 z4 = {0.f, 0.f, 0.f, 0.f};
#pragma unroll
  for (int i = 0; i < 4; ++i)
#pragma unroll
    for (int j = 0; j < 8; ++j) acc[i][j] = z4;

#define RD_B(sl) do { \
    _Pragma("unroll") for (int _j = 0; _j < 4; ++_j) \
      bf03[_j] = *(const half8*)&sm[sl][offB0 + _j * 512]; \
    _Pragma("unroll") for (int _j = 0; _j < 4; ++_j) \
      bf47[_j] = *(const half8*)&sm[sl][offB0 + (4 + _j) * 512]; } while (0)

#define MFMA32(af_) do { \
    _Pragma("unroll") for (int _i = 0; _i < 4; ++_i) \
    _Pragma("unroll") for (int _j = 0; _j < 4; ++_j) \
      acc[_i][_j] = __builtin_amdgcn_mfma_f32_16x16x32_f16(af_[_i], bf03[_j], acc[_i][_j], 0, 0, 0); \
    _Pragma("unroll") for (int _i = 0; _i < 4; ++_i) \
    _Pragma("unroll") for (int _j = 0; _j < 4; ++_j) \
      acc[_i][4 + _j] = __builtin_amdgcn_mfma_f32_16x16x32_f16(af_[_i], bf47[_j], acc[_i][4 + _j], 0, 0, 0); \
  } while (0)

#define BAR() do { asm volatile("" ::: "memory"); __builtin_amdgcn_s_barrier(); asm volatile("" ::: "memory"); } while (0)
#define VM8 asm volatile("s_waitcnt vmcnt(8)" ::: "memory")
#define VM4 asm volatile("s_waitcnt vmcnt(4)" ::: "memory")
#define VM0 asm volatile("s_waitcnt vmcnt(0)" ::: "memory")

  // full tile: BAR | 8 ds_reads B(t) | stage B(t+2) | load A(t+1)->AFn | VM8 | 32 MFMA(AFc)
#define TILE_FULL(sl, s2, kt2, AFc, AFn, ktA) do { \
    BAR(); \
    RD_B(sl); \
    STAGE_B(s2, kt2); \
    RD_AG(AFn, ktA); \
    VM8; \
    MFMA32(AFc); } while (0)
  // tail variants
#define TILE_A(sl, AFc, AFn, ktA, CERT) do { \
    BAR(); \
    RD_B(sl); \
    RD_AG(AFn, ktA); \
    CERT; \
    MFMA32(AFc); } while (0)
#define TILE_LAST(sl, AFc) do { \
    BAR(); \
    RD_B(sl); \
    VM0; \
    MFMA32(AFc); } while (0)

  // ---- prologue: stage B(0),B(1); load A(0)->AFe; VM8 certs B(0) ----
  STAGE_B(0, 0);
  STAGE_B(1, 1);
  RD_AG(AFe, 0);
  VM8;                              // leaves [B(1), A(0)]; B(0) complete
  // (A(0) certified by tile 0's VM8)

  // ---- main loop: tiles 0..59 (stage 2..61, A-loads 1..60); period 6 ----
#pragma unroll 1
  for (int n = 0; n < 10; ++n) {
    const int t6 = 6 * n;
    TILE_FULL(0, 2, t6 + 2, AFe, AFo, t6 + 1);
    TILE_FULL(1, 0, t6 + 3, AFo, AFe, t6 + 2);
    TILE_FULL(2, 1, t6 + 4, AFe, AFo, t6 + 3);
    TILE_FULL(0, 2, t6 + 5, AFo, AFe, t6 + 4);
    TILE_FULL(1, 0, t6 + 6, AFe, AFo, t6 + 5);
    TILE_FULL(2, 1, t6 + 7, AFo, AFe, t6 + 6);
  }
  // ---- tail: tiles 60..63 ----
  TILE_FULL(0, 2, 62, AFe, AFo, 61);          // t=60
  TILE_FULL(1, 0, 63, AFo, AFe, 62);          // t=61; leaves [B(63), A(62)]
  TILE_A(2, AFe, AFo, 63, VM4);               // t=62; VM4 leaves [A(63)]
  TILE_LAST(0, AFo);                          // t=63

  // ---- epilogue ----
  // C/D 16x16 layout: col = rl, row = lg*4 + reg
  if (tN < 128) {
    const int m = tN >> 2;                    // expert (4 N-tiles of 256 per expert)
    float hb[8], w2v[3][8];
#pragma unroll
    for (int j = 0; j < 8; ++j) {
      int gcol = tN * 256 + wn * 128 + j * 16 + rl;     // global big col
      int he   = gcol & (H_DIM - 1);                    // col within expert
      hb[j] = hbias[gcol];
#pragma unroll
      for (int o = 0; o < 3; ++o) w2v[o][j] = W2[((long)m * 3 + o) * H_DIM + he];
    }
#pragma unroll
    for (int i = 0; i < 4; ++i) {
      const int growb = tM * 128 + wm * 64 + i * 16 + lg * 4;
#pragma unroll
      for (int r = 0; r < 4; ++r) {
        int grow = growb + r;
        float hv[8];
#pragma unroll
        for (int j = 0; j < 8; ++j) hv[j] = gelu_f(acc[i][j][r] + hb[j]);
#pragma unroll
        for (int o = 0; o < 3; ++o) {
          float p = 0.f;
#pragma unroll
          for (int j = 0; j < 8; ++j) p = fmaf(hv[j], w2v[o][j], p);
          p += __shfl_xor(p, 1);
          p += __shfl_xor(p, 2);
          p += __shfl_xor(p, 4);
          p += __shfl_xor(p, 8);
          if (rl == o) atomicAdd(&Lout[(long)grow * 96 + m * 3 + o], p);
        }
      }
    }
  } else {
    // raw gate/base pre-activations (global cols 32768..33023)
#pragma unroll
    for (int i = 0; i < 4; ++i) {
      const int growb = tM * 128 + wm * 64 + i * 16 + lg * 4;
#pragma unroll
      for (int r = 0; r < 4; ++r) {
        int grow = growb + r;
        int c0 = wn * 128 + rl;
#pragma unroll
        for (int j = 0; j < 8; ++j)
          qraw[(long)grow * 256 + c0 + j * 16] = acc[i][j][r];
      }
    }
  }
}

// ---------------- post: q normalize, sims, L += base + b2 ----------------
__global__ __launch_bounds__(128) void k_post(const float* __restrict__ qraw,
                                              const float* __restrict__ gate_b,
                                              const float* __restrict__ base_b,
                                              const float* __restrict__ E,
                                              const float* __restrict__ b2,
                                              float* __restrict__ out) {
  const int b = blockIdx.x;
  const int t = threadIdx.x;          // 128
  __shared__ float qs[DE];
  __shared__ float invE[M_EXP];
  __shared__ float wsum[2];
  __shared__ float pA[M_EXP], pB[M_EXP];

  if (t < 32) {
    float ss = 0.f;
    const float* er = E + t * DE;
    for (int e = 0; e < DE; ++e) { float v = er[e]; ss += v * v; }
    invE[t] = 1.0f / fmaxf(sqrtf(ss), 1e-12f);
  }

  float val = qraw[(long)b * 256 + t] + gate_b[t];
  float ss = val * val;
  ss += __shfl_xor(ss, 1);  ss += __shfl_xor(ss, 2);  ss += __shfl_xor(ss, 4);
  ss += __shfl_xor(ss, 8);  ss += __shfl_xor(ss, 16); ss += __shfl_xor(ss, 32);
  if ((t & 63) == 0) wsum[t >> 6] = ss;
  __syncthreads();
  float inv = 1.0f / fmaxf(sqrtf(wsum[0] + wsum[1]), 1e-12f);
  qs[t] = val * inv;
  __syncthreads();

  {
    int m = t & 31, hf = t >> 5;
    const float* er = E + m * DE + hf * 32;
    const float* qq = qs + hf * 32;
    float p = 0.f;
#pragma unroll
    for (int e = 0; e < 32; ++e) p += qq[e] * er[e];
    p += __shfl_xor(p, 32);
    if (t < 32) pA[m] = p;
    else if (t >= 64 && t < 96) pB[m] = p;
    __syncthreads();
    if (t < 32) out[(long)B_ROWS * 96 + (long)b * 32 + t] = (pA[t] + pB[t]) * invE[t];
  }

  if (t < 96) {
    int o = t % 3;
    float bv = qraw[(long)b * 256 + 128 + o] + base_b[o];
    out[(long)b * 96 + t] += bv + b2[t];
  }
}

// ---------------- launch ----------------
extern "C" void kernel_launch(void* const* d_in, const int* in_sizes, int n_in,
                              void* d_out, int out_size, void* d_ws, size_t ws_size,
                              hipStream_t stream) {
  const float* z      = (const float*)d_in[0];
  const float* base_W = (const float*)d_in[1];
  const float* base_b = (const float*)d_in[2];
  const float* gate_W = (const float*)d_in[3];
  const float* gate_b = (const float*)d_in[4];
  const float* E      = (const float*)d_in[5];
  const float* W1     = (const float*)d_in[6];
  const float* b1     = (const float*)d_in[7];
  const float* W2     = (const float*)d_in[8];
  const float* b2     = (const float*)d_in[9];
  float* out = (float*)d_out;

  char* ws = (char*)d_ws;
  const size_t off_zh    = 0;                                   // B*DZ*2 (packed)
  const size_t off_w1h   = off_zh  + (size_t)B_ROWS * DZ * 2;   // NTOT*DZ*2
  const size_t off_hbias = off_w1h + (size_t)NTOT * DZ * 2;     // NBIG*4
  const size_t off_qraw  = off_hbias + (size_t)NBIG * 4;        // B*256*4
  _Float16* zpk   = (_Float16*)(ws + off_zh);
  _Float16* W1h   = (_Float16*)(ws + off_w1h);
  float*    hbias = (float*)(ws + off_hbias);
  float*    qraw  = (float*)(ws + off_qraw);

  // L must start at 0 every call (epilogue atomically accumulates into it)
  hipMemsetAsync(d_out, 0, (size_t)B_ROWS * 96 * sizeof(float), stream);

  k_cvt_z<<<(B_ROWS * DZ) / (256 * 8), 256, 0, stream>>>(z, zpk);
  k_cvt_w1<<<NBIG, 256, 0, stream>>>(W1, E, b1, W1h, hbias);
  k_cvt_small<<<NEXTRA, 256, 0, stream>>>(gate_W, base_W, W1h);
  k_gemm<<<dim3(129, 32), 256, 0, stream>>>(zpk, W1h, hbias, W2, out, qraw);
  k_post<<<B_ROWS, 128, 0, stream>>>(qraw, gate_b, base_b, E, b2, out);
}